// Round 7
// baseline (10154.892 us; speedup 1.0000x reference)
//
#include <hip/hip_runtime.h>
#include <cstddef>
#include <cstdint>

// CustomLSTM: T=512, B=64, I=H=1024, L=2. fp32 in/out, bf16 MFMA internally.
// Fully fused: gates = wi*x_t + wh*h_{t-1} + b computed in ONE persistent
// cooperative kernel per layer (512 steps, 511 grid barriers). No xin GEMM.
#define T_LEN   512
#define BATCH   64
#define IN_DIM  1024
#define HID     1024
#define GATES   4096
#define NLAYERS 2
#define BH      (BATCH * HID)
#define RBLK    256             // persistent blocks; 4 hidden units each

typedef __bf16 bf16;
typedef __bf16 bf16x8 __attribute__((ext_vector_type(8)));
typedef float  f32x4  __attribute__((ext_vector_type(4)));

// ---------------------------------------------------------------------------
// fp32 -> bf16 (RNE), vectorized. n4 = n/4.
// ---------------------------------------------------------------------------
__global__ __launch_bounds__(256) void cvt_bf16(const float* __restrict__ in,
                                                bf16* __restrict__ out, int n4) {
    int i = blockIdx.x * blockDim.x + threadIdx.x;
    if (i >= n4) return;
    float4 v = ((const float4*)in)[i];
    bf16 o[4] = {(bf16)v.x, (bf16)v.y, (bf16)v.z, (bf16)v.w};
    *(uint2*)(out + 4 * (size_t)i) = *(uint2*)o;
}

// ---------------------------------------------------------------------------
// Persistent fused LSTM layer. Datapath pieces are round-6 validated
// (absmax 0.0100): staging layout, 4-chain MFMA fragment mapping, sg
// exchange, packed agent-scope h stores, vmcnt drain, detector barrier.
// New in this round (structural only):
//  - wi rows staged in LDS beside wh rows; per step 64 MFMAs accumulate
//    wi*x_t + wh*h_{t-1} + b into the same 4 chains. No xin buffer.
//  - x-part for step tt+1 is computed BETWEEN arrival-flag and release-poll
//    (x_t is input data, independent of h) -> hides inside the barrier wait.
//  - whole layer in one launch: h history IS the seq buffer hseq[t]
//    (written once at step t, read once at t+1 -> no stale-cache window;
//    t=0 skips the h-MFMA since h(-1)=0). c lives in registers all layer.
// Barrier: per-block flag store (parallel), detector wave in block 0 scans
// 256 flags, writes write-once release word on another line; tight 2^16
// guards degrade any livelock to a wrong answer, never a hang.
// ---------------------------------------------------------------------------
__global__ __launch_bounds__(256) void lstm_layer(
    const bf16*  __restrict__ wi,      // [4H][IN] bf16
    const bf16*  __restrict__ wh,      // [4H][H] bf16
    const float* __restrict__ bih,     // [4H]
    const float* __restrict__ bhh,     // [4H]
    const bf16*  __restrict__ xbf,     // [T][B][H] bf16 layer input
    bf16*        __restrict__ hseq,    // [T][B][H] bf16 h output (= h history)
    float*       __restrict__ outf,    // [T][B][H] fp32 or null (layer 1)
    float*       __restrict__ hf32,    // [B][H] final h
    float*       __restrict__ cbuf,    // [B][H] final c
    unsigned*    __restrict__ bar)     // [512] zeroed: flags[0..255], release[384]
{
    __shared__ bf16  Bi[16 * 1032];    // wi slice, pad 1024->1032
    __shared__ bf16  Bh[16 * 1032];    // wh slice
    __shared__ float sg[4 * 272];      // per-wave gate tile, stride 17

    const int bk   = blockIdx.x;
    const int j0   = bk * 4;
    const int tid  = threadIdx.x;
    const int lane = tid & 63;
    const int wv   = tid >> 6;
    const int m0   = wv * 16;          // batch base for this wave
    const int quad = lane >> 4;
    const int l16  = lane & 15;

    unsigned* flags   = bar;
    unsigned* release = bar + 384;     // different 128B line than flags

    // stage wi+wh rows once: local row = type*4+u -> gate row type*1024+j0+u
    #pragma unroll
    for (int i = 0; i < 8; ++i) {
        int flat = i * 256 + tid;       // 0..2047 (16 rows x 128 uint4)
        int row  = flat >> 7;
        int k16  = flat & 127;
        int grr  = (row >> 2) * 1024 + j0 + (row & 3);
        *(uint4*)&Bi[row * 1032 + k16 * 8] =
            *(const uint4*)(wi + (size_t)grr * IN_DIM + k16 * 8);
        *(uint4*)&Bh[row * 1032 + k16 * 8] =
            *(const uint4*)(wh + (size_t)grr * HID + k16 * 8);
    }

    // this thread's cell: batch cb, unit cu (one cell per thread, all steps)
    const int cb = m0 + l16;
    const int cu = j0 + quad;
    float c = 0.f;                      // c(-1)=0, in a register all layer

    // MFMA D mapping: row = quad*4+r (batch bb+r), col = l16 -> gate row gr
    const int gr = (l16 >> 2) * 1024 + j0 + (l16 & 3);
    const int bb = m0 + quad * 4;
    const float bias = bih[gr] + bhh[gr];

    __syncthreads();                    // LDS staged

    const bf16*  bibase = &Bi[l16 * 1032 + quad * 8];
    const bf16*  bhbase = &Bh[l16 * 1032 + quad * 8];
    const size_t arow   = (size_t)(m0 + l16) * HID + quad * 8;

    f32x4 acc0, acc1, acc2, acc3;
    // prologue: acc = bias + wi*x_0
    {
        const bf16* xp = xbf + arow;
        acc0 = {bias, bias, bias, bias};
        acc1 = {0.f, 0.f, 0.f, 0.f};
        acc2 = {0.f, 0.f, 0.f, 0.f};
        acc3 = {0.f, 0.f, 0.f, 0.f};
        #pragma unroll
        for (int q = 0; q < 8; ++q) {
            const int k0 = q * 32;
            acc0 = __builtin_amdgcn_mfma_f32_16x16x32_bf16(
                *(const bf16x8*)(xp + k0),       *(const bf16x8*)(bibase + k0),       acc0, 0, 0, 0);
            acc1 = __builtin_amdgcn_mfma_f32_16x16x32_bf16(
                *(const bf16x8*)(xp + 256 + k0), *(const bf16x8*)(bibase + 256 + k0), acc1, 0, 0, 0);
            acc2 = __builtin_amdgcn_mfma_f32_16x16x32_bf16(
                *(const bf16x8*)(xp + 512 + k0), *(const bf16x8*)(bibase + 512 + k0), acc2, 0, 0, 0);
            acc3 = __builtin_amdgcn_mfma_f32_16x16x32_bf16(
                *(const bf16x8*)(xp + 768 + k0), *(const bf16x8*)(bibase + 768 + k0), acc3, 0, 0, 0);
        }
    }

    for (int tt = 0; tt < T_LEN; ++tt) {
        if (tt > 0) {
            // wait for h[tt-1] (release-poll half of the split barrier)
            const unsigned ep = (unsigned)tt;
            if (tid == 0) {
                unsigned guard = 0;
                while (__hip_atomic_load(release, __ATOMIC_RELAXED,
                                         __HIP_MEMORY_SCOPE_AGENT) < ep) {
                    __builtin_amdgcn_s_sleep(1);
                    if (++guard > (1u << 16)) break;   // hang-safety valve
                }
            }
            __syncthreads();
            // h-part: acc += wh * h_{tt-1}
            const bf16* hp = hseq + (size_t)(tt - 1) * BH + arow;
            #pragma unroll
            for (int q = 0; q < 8; ++q) {
                const int k0 = q * 32;
                acc0 = __builtin_amdgcn_mfma_f32_16x16x32_bf16(
                    *(const bf16x8*)(hp + k0),       *(const bf16x8*)(bhbase + k0),       acc0, 0, 0, 0);
                acc1 = __builtin_amdgcn_mfma_f32_16x16x32_bf16(
                    *(const bf16x8*)(hp + 256 + k0), *(const bf16x8*)(bhbase + 256 + k0), acc1, 0, 0, 0);
                acc2 = __builtin_amdgcn_mfma_f32_16x16x32_bf16(
                    *(const bf16x8*)(hp + 512 + k0), *(const bf16x8*)(bhbase + 512 + k0), acc2, 0, 0, 0);
                acc3 = __builtin_amdgcn_mfma_f32_16x16x32_bf16(
                    *(const bf16x8*)(hp + 768 + k0), *(const bf16x8*)(bhbase + 768 + k0), acc3, 0, 0, 0);
            }
        }

        f32x4 g4 = (acc0 + acc1) + (acc2 + acc3);

        // intra-wave gate exchange (per-wave sg region; DS in-order per wave)
        #pragma unroll
        for (int r = 0; r < 4; ++r)
            sg[wv * 272 + (quad * 4 + r) * 17 + l16] = g4[r];
        const float* gp = &sg[wv * 272 + l16 * 17];
        float gi = gp[quad], gf = gp[4 + quad], gg = gp[8 + quad], go = gp[12 + quad];

        float si  = 1.f / (1.f + expf(-gi));
        float sf_ = 1.f / (1.f + expf(-gf));
        float so  = 1.f / (1.f + expf(-go));
        float cv  = sf_ * c + si * tanhf(gg);
        float hv  = so * tanhf(cv);
        c = cv;

        const size_t idx = (size_t)cb * HID + cu;
        // pack adjacent units (quad, quad^1) -> one 4B write-through store
        float hvn = __shfl_xor(hv, 16);
        if ((quad & 1) == 0) {
            bf16 hb  = (bf16)hv;
            bf16 hbn = (bf16)hvn;
            unsigned pk = (unsigned)__builtin_bit_cast(unsigned short, hb) |
                          ((unsigned)__builtin_bit_cast(unsigned short, hbn) << 16);
            __hip_atomic_store((unsigned*)(hseq + (size_t)tt * BH + idx), pk,
                               __ATOMIC_RELAXED, __HIP_MEMORY_SCOPE_AGENT);
        }
        if (outf) outf[(size_t)tt * BH + idx] = hv;
        if (tt == T_LEN - 1) hf32[idx] = hv;

        if (tt != T_LEN - 1) {
            // arrival half of the barrier, then x-part for tt+1 (independent
            // of h -> hides inside the barrier window), then detector.
            const unsigned ep = (unsigned)(tt + 1);
            asm volatile("s_waitcnt vmcnt(0)" ::: "memory");  // drain h stores
            __syncthreads();
            if (tid == 0)
                __hip_atomic_store(flags + bk, ep,
                                   __ATOMIC_RELAXED, __HIP_MEMORY_SCOPE_AGENT);

            // acc = bias + wi * x_{tt+1}
            const bf16* xp = xbf + (size_t)(tt + 1) * BH + arow;
            acc0 = {bias, bias, bias, bias};
            acc1 = {0.f, 0.f, 0.f, 0.f};
            acc2 = {0.f, 0.f, 0.f, 0.f};
            acc3 = {0.f, 0.f, 0.f, 0.f};
            #pragma unroll
            for (int q = 0; q < 8; ++q) {
                const int k0 = q * 32;
                acc0 = __builtin_amdgcn_mfma_f32_16x16x32_bf16(
                    *(const bf16x8*)(xp + k0),       *(const bf16x8*)(bibase + k0),       acc0, 0, 0, 0);
                acc1 = __builtin_amdgcn_mfma_f32_16x16x32_bf16(
                    *(const bf16x8*)(xp + 256 + k0), *(const bf16x8*)(bibase + 256 + k0), acc1, 0, 0, 0);
                acc2 = __builtin_amdgcn_mfma_f32_16x16x32_bf16(
                    *(const bf16x8*)(xp + 512 + k0), *(const bf16x8*)(bibase + 512 + k0), acc2, 0, 0, 0);
                acc3 = __builtin_amdgcn_mfma_f32_16x16x32_bf16(
                    *(const bf16x8*)(xp + 768 + k0), *(const bf16x8*)(bibase + 768 + k0), acc3, 0, 0, 0);
            }

            if (bk == 0 && tid < 64) {            // detector wave
                unsigned guard = 0;
                for (;;) {
                    unsigned f0 = __hip_atomic_load(flags + tid,
                                   __ATOMIC_RELAXED, __HIP_MEMORY_SCOPE_AGENT);
                    unsigned f1 = __hip_atomic_load(flags + 64 + tid,
                                   __ATOMIC_RELAXED, __HIP_MEMORY_SCOPE_AGENT);
                    unsigned f2 = __hip_atomic_load(flags + 128 + tid,
                                   __ATOMIC_RELAXED, __HIP_MEMORY_SCOPE_AGENT);
                    unsigned f3 = __hip_atomic_load(flags + 192 + tid,
                                   __ATOMIC_RELAXED, __HIP_MEMORY_SCOPE_AGENT);
                    if (__all(f0 >= ep && f1 >= ep && f2 >= ep && f3 >= ep)) break;
                    __builtin_amdgcn_s_sleep(1);
                    if (++guard > (1u << 16)) break;   // hang-safety valve
                }
                if (tid == 0)
                    __hip_atomic_store(release, ep,
                                       __ATOMIC_RELAXED, __HIP_MEMORY_SCOPE_AGENT);
            }
        }
    }

    cbuf[(size_t)cb * HID + cu] = c;    // normal store; kernel-end release
}

// ---------------------------------------------------------------------------
extern "C" void kernel_launch(void* const* d_in, const int* in_sizes, int n_in,
                              void* d_out, int out_size, void* d_ws, size_t ws_size,
                              hipStream_t stream) {
    const float* x    = (const float*)d_in[0];
    const float* w_ih = (const float*)d_in[1];
    const float* w_hh = (const float*)d_in[2];
    const float* b_ih = (const float*)d_in[3];
    const float* b_hh = (const float*)d_in[4];
    float* out = (float*)d_out;

    // ws layout (~152.5 MB, within prior rounds' footprint):
    //   cbuf   : B*H fp32, hf32: B*H fp32
    //   seq1bf : T*B*H bf16 = 64 MB (layer-0 h/seq; layer-1 x input)
    //   xh0    : T*B*H bf16 = 64 MB (layer 0: x in bf16; layer 1: h buffer)
    //   wibf   : 4H*I bf16 = 16 MB, whbf: 4H*H bf16 = 8 MB (per-layer reuse)
    //   bar    : 512 unsigned (flags[0..255] + release[384])
    float* cbuf = (float*)d_ws;
    float* hf32 = cbuf + (size_t)BATCH * HID;
    bf16* seq1bf = (bf16*)(hf32 + (size_t)BATCH * HID);
    bf16* xh0    = seq1bf + (size_t)T_LEN * BATCH * HID;
    bf16* wibf   = xh0 + (size_t)T_LEN * BATCH * HID;
    bf16* whbf   = wibf + (size_t)GATES * IN_DIM;
    unsigned* bar = (unsigned*)(whbf + (size_t)GATES * HID);

    const size_t seqE = (size_t)T_LEN * BATCH * HID;
    const size_t BHs  = (size_t)BATCH * HID;

    // x -> bf16 once (read by layer 0 as the MFMA A-operand)
    cvt_bf16<<<(int)(seqE / 4 + 255) / 256, 256, 0, stream>>>(x, xh0, (int)(seqE / 4));

    for (int l = 0; l < NLAYERS; ++l) {
        const float* wi = w_ih + (size_t)l * GATES * IN_DIM;
        const float* wh = w_hh + (size_t)l * GATES * HID;
        const float* bi = b_ih + (size_t)l * GATES;
        const float* bh = b_hh + (size_t)l * GATES;

        // weights -> bf16 (per-layer buffers, reused across layers)
        cvt_bf16<<<(GATES * IN_DIM / 4 + 255) / 256, 256, 0, stream>>>(wi, wibf, GATES * IN_DIM / 4);
        cvt_bf16<<<(GATES * HID / 4 + 255) / 256, 256, 0, stream>>>(wh, whbf, GATES * HID / 4);

        hipMemsetAsync(bar, 0, 512 * sizeof(unsigned), stream);

        const bf16* xin_l = (l == 0) ? xh0 : seq1bf;
        bf16*       hseq  = (l == 0) ? seq1bf : xh0;    // layer-1 h aliases x0 region
        float*      outf  = (l == 1) ? out : nullptr;

        const bf16*  wic = wibf;  const bf16* whc = whbf;
        const float* bic = bi;    const float* bhc = bh;
        float* hfc = hf32;  float* cbc = cbuf;  unsigned* barc = bar;
        void* args[10] = { (void*)&wic, (void*)&whc, (void*)&bic, (void*)&bhc,
                           (void*)&xin_l, (void*)&hseq, (void*)&outf,
                           (void*)&hfc, (void*)&cbc, (void*)&barc };
        hipLaunchCooperativeKernel((void*)lstm_layer, dim3(RBLK), dim3(256),
                                   args, 0, stream);

        hipMemcpyAsync(out + seqE + (size_t)l * BHs, hf32, BHs * sizeof(float),
                       hipMemcpyDeviceToDevice, stream);
        hipMemcpyAsync(out + seqE + (size_t)(NLAYERS + l) * BHs, cbuf, BHs * sizeof(float),
                       hipMemcpyDeviceToDevice, stream);
    }
}

// Round 8
// 9227.656 us; speedup vs baseline: 1.1005x; 1.1005x over previous
//
#include <hip/hip_runtime.h>
#include <cstddef>
#include <cstdint>

// CustomLSTM: T=512, B=64, I=H=1024, L=2. fp32 in/out, bf16 MFMA internally.
// Layer-pipelined persistent kernel: ONE cooperative launch runs BOTH layers
// with a one-step skew (macro-step s: L0 computes h0[s], L1 computes h1[s-1]).
// Sequential depth 1024 -> 513. Per-layer step datapath is round-7 verbatim
// (hardware-validated, absmax 0.0103). No xin GEMM, no xin buffer.
#define T_LEN   512
#define BATCH   64
#define IN_DIM  1024
#define HID     1024
#define GATES   4096
#define NLAYERS 2
#define BH      (BATCH * HID)
#define LBLK    256             // blocks per layer (4 hidden units each)
#define NBLK    512             // total persistent blocks (2 per CU)

typedef __bf16 bf16;
typedef __bf16 bf16x8 __attribute__((ext_vector_type(8)));
typedef float  f32x4  __attribute__((ext_vector_type(4)));

// ---------------------------------------------------------------------------
// fp32 -> bf16 (RNE), vectorized. n4 = n/4.
// ---------------------------------------------------------------------------
__global__ __launch_bounds__(256) void cvt_bf16(const float* __restrict__ in,
                                                bf16* __restrict__ out, int n4) {
    int i = blockIdx.x * blockDim.x + threadIdx.x;
    if (i >= n4) return;
    float4 v = ((const float4*)in)[i];
    bf16 o[4] = {(bf16)v.x, (bf16)v.y, (bf16)v.z, (bf16)v.w};
    *(uint2*)(out + 4 * (size_t)i) = *(uint2*)o;
}

// 4-chain K=1024 GEMV-accumulate (round-7 verbatim fragment loop)
#define GEMV8(XP, BB)                                                          \
    _Pragma("unroll")                                                          \
    for (int q = 0; q < 8; ++q) {                                              \
        const int k0 = q * 32;                                                 \
        acc0 = __builtin_amdgcn_mfma_f32_16x16x32_bf16(                        \
            *(const bf16x8*)((XP) + k0),       *(const bf16x8*)((BB) + k0),       acc0, 0, 0, 0); \
        acc1 = __builtin_amdgcn_mfma_f32_16x16x32_bf16(                        \
            *(const bf16x8*)((XP) + 256 + k0), *(const bf16x8*)((BB) + 256 + k0), acc1, 0, 0, 0); \
        acc2 = __builtin_amdgcn_mfma_f32_16x16x32_bf16(                        \
            *(const bf16x8*)((XP) + 512 + k0), *(const bf16x8*)((BB) + 512 + k0), acc2, 0, 0, 0); \
        acc3 = __builtin_amdgcn_mfma_f32_16x16x32_bf16(                        \
            *(const bf16x8*)((XP) + 768 + k0), *(const bf16x8*)((BB) + 768 + k0), acc3, 0, 0, 0); \
    }

// ---------------------------------------------------------------------------
// Pipelined two-layer persistent LSTM.
// Blocks bk<256: layer 0 (units j0=4*bk). Blocks bk>=256: layer 1 (j0=4*(bk-256)).
// Macro-step s in [0,513): L0 active for s<512 (t=s); L1 active for s>=1 (t=s-1).
//  - L0: accs carry bias + wi0*x[t] (pre-computed in the previous barrier's
//    shadow window, round-7 trick); post-barrier adds wh0*h0[t-1].
//  - L1: post-barrier computes bias + wi1*h0[t] + wh1*h1[t-1] (h0[t] only
//    becomes visible at the barrier entering step s, so nothing to shadow).
// h0seq/h1seq: full-T write-once-read-once bf16 buffers (validated
// staleness-free pattern: agent write-through stores + vmcnt drain; readers'
// caches never hold a pre-write copy within the launch; kernel-boundary
// coherence across bench iterations proven rounds 3-7).
// Barrier (round-6/7 validated detector form, 512 flags): per-block flag
// store, detector wave in block 511 (L1: idle shadow -> delays nobody),
// write-once release word; tight 2^16 guards degrade any livelock to a wrong
// answer, never a hang.
// ---------------------------------------------------------------------------
__global__ __launch_bounds__(256) void lstm_pipe(
    const bf16*  __restrict__ wi0,     // [4H][IN] bf16
    const bf16*  __restrict__ wh0,     // [4H][H] bf16
    const bf16*  __restrict__ wi1,     // [4H][H] bf16
    const bf16*  __restrict__ wh1,     // [4H][H] bf16
    const float* __restrict__ bih,     // [L][4H]
    const float* __restrict__ bhh,     // [L][4H]
    const bf16*  __restrict__ xbf,     // [T][B][H] bf16 network input
    bf16*        __restrict__ h0seq,   // [T][B][H] bf16 layer-0 h
    bf16*        __restrict__ h1seq,   // [T][B][H] bf16 layer-1 h
    float*       __restrict__ outf,    // [T][B][H] fp32 final seq output
    float*       __restrict__ hf0,     // [B][H] final h, layer 0
    float*       __restrict__ hf1,     // [B][H] final h, layer 1
    float*       __restrict__ cb0,     // [B][H] final c, layer 0
    float*       __restrict__ cb1,     // [B][H] final c, layer 1
    unsigned*    __restrict__ bar)     // [1024] zeroed: flags[0..511], release[768]
{
    __shared__ bf16  Bi[16 * 1032];    // wi slice, pad 1024->1032
    __shared__ bf16  Bh[16 * 1032];    // wh slice
    __shared__ float sg[4 * 272];      // per-wave gate tile, stride 17

    const int bk   = blockIdx.x;
    const bool isL1 = (bk >= LBLK);
    const int lk   = bk & (LBLK - 1);
    const int j0   = lk * 4;
    const int tid  = threadIdx.x;
    const int lane = tid & 63;
    const int wv   = tid >> 6;
    const int m0   = wv * 16;          // batch base for this wave
    const int quad = lane >> 4;
    const int l16  = lane & 15;

    unsigned* flags   = bar;
    unsigned* release = bar + 768;     // different 128B line than flags

    const bf16* wiL = isL1 ? wi1 : wi0;
    const bf16* whL = isL1 ? wh1 : wh0;
    const int   boff = isL1 ? GATES : 0;
    bf16*       hW  = isL1 ? h1seq : h0seq;   // this layer's h output buffer
    float*      hfL = isL1 ? hf1 : hf0;
    float*      cbL = isL1 ? cb1 : cb0;

    // stage wi+wh rows once: local row = type*4+u -> gate row type*1024+j0+u
    #pragma unroll
    for (int i = 0; i < 8; ++i) {
        int flat = i * 256 + tid;       // 0..2047 (16 rows x 128 uint4)
        int row  = flat >> 7;
        int k16  = flat & 127;
        int grr  = (row >> 2) * 1024 + j0 + (row & 3);
        *(uint4*)&Bi[row * 1032 + k16 * 8] =
            *(const uint4*)(wiL + (size_t)grr * IN_DIM + k16 * 8);
        *(uint4*)&Bh[row * 1032 + k16 * 8] =
            *(const uint4*)(whL + (size_t)grr * HID + k16 * 8);
    }

    // this thread's cell: batch cb, unit cu (one cell per thread, all steps)
    const int cb = m0 + l16;
    const int cu = j0 + quad;
    float c = 0.f;                      // c(-1)=0, register-resident all run

    // MFMA D mapping: row = quad*4+r (batch bb+r), col = l16 -> gate row gr
    const int gr = (l16 >> 2) * 1024 + j0 + (l16 & 3);
    const float bias = bih[boff + gr] + bhh[boff + gr];

    __syncthreads();                    // LDS staged

    const bf16*  bibase = &Bi[l16 * 1032 + quad * 8];
    const bf16*  bhbase = &Bh[l16 * 1032 + quad * 8];
    const size_t arow   = (size_t)(m0 + l16) * HID + quad * 8;

    f32x4 acc0, acc1, acc2, acc3;
    if (!isL1) {                        // L0 prologue: acc = bias + wi0*x_0
        const bf16* xp = xbf + arow;
        acc0 = {bias, bias, bias, bias};
        acc1 = {0.f, 0.f, 0.f, 0.f};
        acc2 = {0.f, 0.f, 0.f, 0.f};
        acc3 = {0.f, 0.f, 0.f, 0.f};
        GEMV8(xp, bibase)
    }

    for (int s = 0; s < T_LEN + 1; ++s) {
        if (s > 0) {
            // wait for macro-step s-1's outputs (release-poll)
            const unsigned ep = (unsigned)s;
            if (tid == 0) {
                unsigned guard = 0;
                while (__hip_atomic_load(release, __ATOMIC_RELAXED,
                                         __HIP_MEMORY_SCOPE_AGENT) < ep) {
                    __builtin_amdgcn_s_sleep(1);
                    if (++guard > (1u << 16)) break;   // hang-safety valve
                }
            }
            __syncthreads();
        }

        const bool active = isL1 ? (s >= 1) : (s < T_LEN);
        if (active) {
            const int t = isL1 ? (s - 1) : s;
            if (isL1) {
                // acc = bias + wi1*h0[t] (+ wh1*h1[t-1])
                const bf16* xp = h0seq + (size_t)t * BH + arow;
                acc0 = {bias, bias, bias, bias};
                acc1 = {0.f, 0.f, 0.f, 0.f};
                acc2 = {0.f, 0.f, 0.f, 0.f};
                acc3 = {0.f, 0.f, 0.f, 0.f};
                GEMV8(xp, bibase)
                if (t > 0) {
                    const bf16* hp = h1seq + (size_t)(t - 1) * BH + arow;
                    GEMV8(hp, bhbase)
                }
            } else {
                if (t > 0) {            // accs carry bias + wi0*x[t] already
                    const bf16* hp = h0seq + (size_t)(t - 1) * BH + arow;
                    GEMV8(hp, bhbase)
                }
            }

            f32x4 g4 = (acc0 + acc1) + (acc2 + acc3);

            // intra-wave gate exchange (per-wave sg region; DS in-order)
            #pragma unroll
            for (int r = 0; r < 4; ++r)
                sg[wv * 272 + (quad * 4 + r) * 17 + l16] = g4[r];
            const float* gp = &sg[wv * 272 + l16 * 17];
            float gi = gp[quad], gf = gp[4 + quad], gg = gp[8 + quad], go = gp[12 + quad];

            float si  = 1.f / (1.f + expf(-gi));
            float sf_ = 1.f / (1.f + expf(-gf));
            float so  = 1.f / (1.f + expf(-go));
            float cv  = sf_ * c + si * tanhf(gg);
            float hv  = so * tanhf(cv);
            c = cv;

            const size_t idx = (size_t)cb * HID + cu;
            // pack adjacent units (quad, quad^1) -> one 4B write-through store
            float hvn = __shfl_xor(hv, 16);
            if ((quad & 1) == 0) {
                bf16 hb  = (bf16)hv;
                bf16 hbn = (bf16)hvn;
                unsigned pk = (unsigned)__builtin_bit_cast(unsigned short, hb) |
                              ((unsigned)__builtin_bit_cast(unsigned short, hbn) << 16);
                __hip_atomic_store((unsigned*)(hW + (size_t)t * BH + idx), pk,
                                   __ATOMIC_RELAXED, __HIP_MEMORY_SCOPE_AGENT);
            }
            if (isL1) outf[(size_t)t * BH + idx] = hv;
            if (t == T_LEN - 1) hfL[idx] = hv;
        }

        if (s < T_LEN) {
            const unsigned ep = (unsigned)(s + 1);
            asm volatile("s_waitcnt vmcnt(0)" ::: "memory");  // drain h stores
            __syncthreads();
            if (tid == 0)
                __hip_atomic_store(flags + bk, ep,
                                   __ATOMIC_RELAXED, __HIP_MEMORY_SCOPE_AGENT);

            // L0 shadow work: acc = bias + wi0*x[s+1] while barrier resolves
            if (!isL1 && s < T_LEN - 1) {
                const bf16* xp = xbf + (size_t)(s + 1) * BH + arow;
                acc0 = {bias, bias, bias, bias};
                acc1 = {0.f, 0.f, 0.f, 0.f};
                acc2 = {0.f, 0.f, 0.f, 0.f};
                acc3 = {0.f, 0.f, 0.f, 0.f};
                GEMV8(xp, bibase)
            }

            if (bk == NBLK - 1 && tid < 64) {     // detector wave (L1 block:
                unsigned guard = 0;               //  idle shadow, delays nobody)
                for (;;) {
                    bool good = true;
                    #pragma unroll
                    for (int j = 0; j < 8; ++j) {
                        unsigned f = __hip_atomic_load(flags + tid + 64 * j,
                                       __ATOMIC_RELAXED, __HIP_MEMORY_SCOPE_AGENT);
                        good = good && (f >= ep);
                    }
                    if (__all(good)) break;
                    __builtin_amdgcn_s_sleep(1);
                    if (++guard > (1u << 16)) break;   // hang-safety valve
                }
                if (tid == 0)
                    __hip_atomic_store(release, ep,
                                       __ATOMIC_RELAXED, __HIP_MEMORY_SCOPE_AGENT);
            }
        }
    }

    cbL[(size_t)cb * HID + cu] = c;     // normal store; kernel-end release
}

// ---------------------------------------------------------------------------
extern "C" void kernel_launch(void* const* d_in, const int* in_sizes, int n_in,
                              void* d_out, int out_size, void* d_ws, size_t ws_size,
                              hipStream_t stream) {
    const float* x    = (const float*)d_in[0];
    const float* w_ih = (const float*)d_in[1];
    const float* w_hh = (const float*)d_in[2];
    const float* b_ih = (const float*)d_in[3];
    const float* b_hh = (const float*)d_in[4];
    float* out = (float*)d_out;

    // ws layout (~225 MB):
    //   xbf    : T*B*H bf16 = 64 MB (network input, bf16)
    //   h0seq  : T*B*H bf16 = 64 MB (layer-0 h, write-once-read-once)
    //   h1seq  : T*B*H bf16 = 64 MB (layer-1 h)
    //   wi0b/wh0b/wi1b/wh1b : 8 MB each bf16
    //   hf0,hf1,cb0,cb1 : B*H fp32 each
    //   bar    : 1024 unsigned (flags[0..511] + release[768])
    const size_t seqE = (size_t)T_LEN * BATCH * HID;
    const size_t BHs  = (size_t)BATCH * HID;

    bf16* xbf   = (bf16*)d_ws;
    bf16* h0seq = xbf + seqE;
    bf16* h1seq = h0seq + seqE;
    bf16* wi0b  = h1seq + seqE;
    bf16* wh0b  = wi0b + (size_t)GATES * IN_DIM;
    bf16* wi1b  = wh0b + (size_t)GATES * HID;
    bf16* wh1b  = wi1b + (size_t)GATES * HID;
    float* hf0  = (float*)(wh1b + (size_t)GATES * HID);
    float* hf1  = hf0 + BHs;
    float* cb0  = hf1 + BHs;
    float* cb1  = cb0 + BHs;
    unsigned* bar = (unsigned*)(cb1 + BHs);

    // conversions (all parallel, off the critical chain)
    cvt_bf16<<<(int)(seqE / 4 + 255) / 256, 256, 0, stream>>>(x, xbf, (int)(seqE / 4));
    cvt_bf16<<<(GATES * IN_DIM / 4 + 255) / 256, 256, 0, stream>>>(
        w_ih, wi0b, GATES * IN_DIM / 4);
    cvt_bf16<<<(GATES * HID / 4 + 255) / 256, 256, 0, stream>>>(
        w_hh, wh0b, GATES * HID / 4);
    cvt_bf16<<<(GATES * HID / 4 + 255) / 256, 256, 0, stream>>>(
        w_ih + (size_t)GATES * IN_DIM, wi1b, GATES * HID / 4);
    cvt_bf16<<<(GATES * HID / 4 + 255) / 256, 256, 0, stream>>>(
        w_hh + (size_t)GATES * HID, wh1b, GATES * HID / 4);

    hipMemsetAsync(bar, 0, 1024 * sizeof(unsigned), stream);

    void* args[15] = { (void*)&wi0b, (void*)&wh0b, (void*)&wi1b, (void*)&wh1b,
                       (void*)&b_ih, (void*)&b_hh, (void*)&xbf,
                       (void*)&h0seq, (void*)&h1seq, (void*)&out,
                       (void*)&hf0, (void*)&hf1, (void*)&cb0, (void*)&cb1,
                       (void*)&bar };
    hipLaunchCooperativeKernel((void*)lstm_pipe, dim3(NBLK), dim3(256),
                               args, 0, stream);

    hipMemcpyAsync(out + seqE,           hf0, BHs * sizeof(float),
                   hipMemcpyDeviceToDevice, stream);
    hipMemcpyAsync(out + seqE + BHs,     hf1, BHs * sizeof(float),
                   hipMemcpyDeviceToDevice, stream);
    hipMemcpyAsync(out + seqE + 2 * BHs, cb0, BHs * sizeof(float),
                   hipMemcpyDeviceToDevice, stream);
    hipMemcpyAsync(out + seqE + 3 * BHs, cb1, BHs * sizeof(float),
                   hipMemcpyDeviceToDevice, stream);
}

// Round 9
// 8704.198 us; speedup vs baseline: 1.1667x; 1.0601x over previous
//
#include <hip/hip_runtime.h>
#include <cstddef>
#include <cstdint>

// CustomLSTM: T=512, B=64, I=H=1024, L=2. fp32 in/out, bf16 MFMA internally.
// Two-layer 2-step-skew pipeline in ONE persistent cooperative kernel:
// macro-step s computes h0[s] and h1[s-2]; wi-projections for BOTH layers are
// computed in the barrier shadow (h0[s-1] is visible when step s opens), so
// each layer's post-barrier critical path is ONE GEMV. 514 barriers serve
// 1024 logical steps.
#define T_LEN   512
#define BATCH   64
#define IN_DIM  1024
#define HID     1024
#define GATES   4096
#define NLAYERS 2
#define BH      (BATCH * HID)
#define RBLK    256             // persistent blocks; 4 units per layer each; 1/CU

typedef __bf16 bf16;
typedef __bf16 bf16x8 __attribute__((ext_vector_type(8)));
typedef float  f32x4  __attribute__((ext_vector_type(4)));

// ---------------------------------------------------------------------------
// fp32 -> bf16 (RNE), vectorized. n4 = n/4.
// ---------------------------------------------------------------------------
__global__ __launch_bounds__(256) void cvt_bf16(const float* __restrict__ in,
                                                bf16* __restrict__ out, int n4) {
    int i = blockIdx.x * blockDim.x + threadIdx.x;
    if (i >= n4) return;
    float4 v = ((const float4*)in)[i];
    bf16 o[4] = {(bf16)v.x, (bf16)v.y, (bf16)v.z, (bf16)v.w};
    *(uint2*)(out + 4 * (size_t)i) = *(uint2*)o;
}

// 4-chain K=1024 GEMV-accumulate (round-6/7 validated fragment loop; static
// indices only -> stays in registers)
__device__ __forceinline__ void gemv8(f32x4 acc[4], const bf16* __restrict__ xp,
                                      const bf16* __restrict__ bb) {
    #pragma unroll
    for (int q = 0; q < 8; ++q) {
        const int k0 = q * 32;
        #pragma unroll
        for (int ch = 0; ch < 4; ++ch)
            acc[ch] = __builtin_amdgcn_mfma_f32_16x16x32_bf16(
                *(const bf16x8*)(xp + ch * 256 + k0),
                *(const bf16x8*)(bb + ch * 256 + k0), acc[ch], 0, 0, 0);
    }
}

// ---------------------------------------------------------------------------
// Fused pipelined two-layer persistent LSTM. Block bk owns units j0=4bk..+3
// of BOTH layers (four 16-row weight slices in LDS, staged once).
// Schedule (macro-step s in [0, 513]):
//   scan barrier (wave 0 scans all 256 flags; no detector, no release hop)
//   L0 critical (s<=511):  h0[s]   = act(pre0[s]   + wh0*h0[s-1])
//   L1 critical (s>=2):    h1[s-2] = act(pre1[s-2] + wh1*h1[s-3])
//   drain + flag(s+1)
//   shadows (overlap other blocks' tails + flag propagation):
//     pre0[s+1] = b0 + wi0*x[s+1]         (s<=510)
//     pre1[s-1] = b1 + wi1*h0[s-1]        (1<=s<=512; h0[s-1] visible since
//                                          the barrier that OPENED step s)
// All datapath pieces (staging layout, fragment mappings, sg exchange, packed
// agent write-through h stores, vmcnt drain, flag-store pattern) are verbatim
// from rounds 6-8 (hardware-validated, absmax 0.0100-0.0103).
// h0seq/h1seq are write-once-read-once full-T buffers (validated pattern).
// Bounded spins (2^13 passes) keep any failure hang-safe.
// ---------------------------------------------------------------------------
__global__ __launch_bounds__(256) void lstm_fused(
    const bf16*  __restrict__ wi0,     // [4H][IN] bf16
    const bf16*  __restrict__ wh0,     // [4H][H] bf16
    const bf16*  __restrict__ wi1,     // [4H][H] bf16
    const bf16*  __restrict__ wh1,     // [4H][H] bf16
    const float* __restrict__ bih,     // [L][4H]
    const float* __restrict__ bhh,     // [L][4H]
    const bf16*  __restrict__ xbf,     // [T][B][H] bf16 network input
    bf16*        __restrict__ h0seq,   // [T][B][H] bf16 layer-0 h
    bf16*        __restrict__ h1seq,   // [T][B][H] bf16 layer-1 h
    float*       __restrict__ outf,    // [T][B][H] fp32 final seq output
    float*       __restrict__ hf0,     // [B][H] final h, layer 0
    float*       __restrict__ hf1,     // [B][H] final h, layer 1
    float*       __restrict__ cb0,     // [B][H] final c, layer 0
    float*       __restrict__ cb1,     // [B][H] final c, layer 1
    unsigned*    __restrict__ flags)   // [512] zeroed before launch
{
    __shared__ bf16  B0i[16 * 1032];   // wi0 slice, pad 1024->1032
    __shared__ bf16  B0h[16 * 1032];   // wh0 slice
    __shared__ bf16  B1i[16 * 1032];   // wi1 slice
    __shared__ bf16  B1h[16 * 1032];   // wh1 slice
    __shared__ float sg[4 * 272];      // per-wave gate tile, stride 17

    const int bk   = blockIdx.x;
    const int j0   = bk * 4;
    const int tid  = threadIdx.x;
    const int lane = tid & 63;
    const int wv   = tid >> 6;
    const int m0   = wv * 16;          // batch base for this wave
    const int quad = lane >> 4;
    const int l16  = lane & 15;

    // stage 4 weight slices once: local row = type*4+u -> gate row
    // type*1024 + j0 + u  (16 rows x 128 uint4 each)
    #pragma unroll
    for (int i = 0; i < 8; ++i) {
        int flat = i * 256 + tid;       // 0..2047
        int row  = flat >> 7;
        int k16  = flat & 127;
        int grr  = (row >> 2) * 1024 + j0 + (row & 3);
        *(uint4*)&B0i[row * 1032 + k16 * 8] =
            *(const uint4*)(wi0 + (size_t)grr * IN_DIM + k16 * 8);
        *(uint4*)&B0h[row * 1032 + k16 * 8] =
            *(const uint4*)(wh0 + (size_t)grr * HID + k16 * 8);
        *(uint4*)&B1i[row * 1032 + k16 * 8] =
            *(const uint4*)(wi1 + (size_t)grr * HID + k16 * 8);
        *(uint4*)&B1h[row * 1032 + k16 * 8] =
            *(const uint4*)(wh1 + (size_t)grr * HID + k16 * 8);
    }

    // this thread's cell (same unit group in both layers): batch cb, unit cu
    const int cb = m0 + l16;
    const int cu = j0 + quad;
    float c0 = 0.f, c1 = 0.f;           // register-resident all run

    // MFMA D mapping: row = quad*4+r (batch), col = l16 -> gate row gr
    const int gr = (l16 >> 2) * 1024 + j0 + (l16 & 3);
    const float bias0 = bih[gr] + bhh[gr];
    const float bias1 = bih[GATES + gr] + bhh[GATES + gr];

    __syncthreads();                    // LDS staged

    const bf16*  b0i = &B0i[l16 * 1032 + quad * 8];
    const bf16*  b0h = &B0h[l16 * 1032 + quad * 8];
    const bf16*  b1i = &B1i[l16 * 1032 + quad * 8];
    const bf16*  b1h = &B1h[l16 * 1032 + quad * 8];
    const size_t arow = (size_t)(m0 + l16) * HID + quad * 8;
    const size_t idx  = (size_t)cb * HID + cu;

    f32x4 p0[4], p1[4] = {};
    // prologue: pre0[0] = bias0 + wi0*x[0]
    p0[0] = {bias0, bias0, bias0, bias0};
    p0[1] = {0.f, 0.f, 0.f, 0.f};
    p0[2] = {0.f, 0.f, 0.f, 0.f};
    p0[3] = {0.f, 0.f, 0.f, 0.f};
    gemv8(p0, xbf + arow, b0i);

    for (int s = 0; s <= T_LEN + 1; ++s) {        // 514 macro-steps
        if (s > 0) {
            // all-scan barrier: wave 0 scans all 256 flags (no release hop)
            const unsigned ep = (unsigned)s;
            if (wv == 0) {
                unsigned guard = 0;
                for (;;) {
                    bool good = true;
                    #pragma unroll
                    for (int j = 0; j < 4; ++j) {
                        unsigned f = __hip_atomic_load(flags + lane + 64 * j,
                                       __ATOMIC_RELAXED, __HIP_MEMORY_SCOPE_AGENT);
                        good = good && (f >= ep);
                    }
                    if (__all(good)) break;
                    __builtin_amdgcn_s_sleep(1);
                    if (++guard > (1u << 13)) break;   // hang-safety valve
                }
            }
            __syncthreads();
        }

        // ---- L0 critical: h0[s] = act(pre0[s] + wh0*h0[s-1]) ----
        if (s < T_LEN) {
            if (s > 0) gemv8(p0, h0seq + (size_t)(s - 1) * BH + arow, b0h);
            f32x4 g4 = (p0[0] + p0[1]) + (p0[2] + p0[3]);
            #pragma unroll
            for (int r = 0; r < 4; ++r)
                sg[wv * 272 + (quad * 4 + r) * 17 + l16] = g4[r];
            const float* gp = &sg[wv * 272 + l16 * 17];
            float gi = gp[quad], gf = gp[4 + quad], gg = gp[8 + quad], go = gp[12 + quad];
            float si  = 1.f / (1.f + expf(-gi));
            float sf_ = 1.f / (1.f + expf(-gf));
            float so  = 1.f / (1.f + expf(-go));
            float cv  = sf_ * c0 + si * tanhf(gg);
            float hv  = so * tanhf(cv);
            c0 = cv;
            float hvn = __shfl_xor(hv, 16);
            if ((quad & 1) == 0) {
                bf16 hb  = (bf16)hv;
                bf16 hbn = (bf16)hvn;
                unsigned pk = (unsigned)__builtin_bit_cast(unsigned short, hb) |
                              ((unsigned)__builtin_bit_cast(unsigned short, hbn) << 16);
                __hip_atomic_store((unsigned*)(h0seq + (size_t)s * BH + idx), pk,
                                   __ATOMIC_RELAXED, __HIP_MEMORY_SCOPE_AGENT);
            }
            if (s == T_LEN - 1) hf0[idx] = hv;
        }

        // ---- L1 critical: h1[s-2] = act(pre1[s-2] + wh1*h1[s-3]) ----
        if (s >= 2) {
            const int t = s - 2;
            if (t > 0) gemv8(p1, h1seq + (size_t)(t - 1) * BH + arow, b1h);
            f32x4 g4 = (p1[0] + p1[1]) + (p1[2] + p1[3]);
            #pragma unroll
            for (int r = 0; r < 4; ++r)
                sg[wv * 272 + (quad * 4 + r) * 17 + l16] = g4[r];
            const float* gp = &sg[wv * 272 + l16 * 17];
            float gi = gp[quad], gf = gp[4 + quad], gg = gp[8 + quad], go = gp[12 + quad];
            float si  = 1.f / (1.f + expf(-gi));
            float sf_ = 1.f / (1.f + expf(-gf));
            float so  = 1.f / (1.f + expf(-go));
            float cv  = sf_ * c1 + si * tanhf(gg);
            float hv  = so * tanhf(cv);
            c1 = cv;
            float hvn = __shfl_xor(hv, 16);
            if ((quad & 1) == 0) {
                bf16 hb  = (bf16)hv;
                bf16 hbn = (bf16)hvn;
                unsigned pk = (unsigned)__builtin_bit_cast(unsigned short, hb) |
                              ((unsigned)__builtin_bit_cast(unsigned short, hbn) << 16);
                __hip_atomic_store((unsigned*)(h1seq + (size_t)t * BH + idx), pk,
                                   __ATOMIC_RELAXED, __HIP_MEMORY_SCOPE_AGENT);
            }
            outf[(size_t)t * BH + idx] = hv;
            if (t == T_LEN - 1) hf1[idx] = hv;
        }

        if (s <= T_LEN) {
            // drain h stores, arrive, then shadow GEMVs (overlap barrier)
            asm volatile("s_waitcnt vmcnt(0)" ::: "memory");
            __syncthreads();
            if (tid == 0)
                __hip_atomic_store(flags + bk, (unsigned)(s + 1),
                                   __ATOMIC_RELAXED, __HIP_MEMORY_SCOPE_AGENT);

            if (s < T_LEN - 1) {        // pre0[s+1] = bias0 + wi0*x[s+1]
                p0[0] = {bias0, bias0, bias0, bias0};
                p0[1] = {0.f, 0.f, 0.f, 0.f};
                p0[2] = {0.f, 0.f, 0.f, 0.f};
                p0[3] = {0.f, 0.f, 0.f, 0.f};
                gemv8(p0, xbf + (size_t)(s + 1) * BH + arow, b0i);
            }
            if (s >= 1) {               // pre1[s-1] = bias1 + wi1*h0[s-1]
                p1[0] = {bias1, bias1, bias1, bias1};
                p1[1] = {0.f, 0.f, 0.f, 0.f};
                p1[2] = {0.f, 0.f, 0.f, 0.f};
                p1[3] = {0.f, 0.f, 0.f, 0.f};
                gemv8(p1, h0seq + (size_t)(s - 1) * BH + arow, b1i);
            }
        }
    }

    cb0[idx] = c0;                      // normal stores; kernel-end release
    cb1[idx] = c1;
}

// ---------------------------------------------------------------------------
extern "C" void kernel_launch(void* const* d_in, const int* in_sizes, int n_in,
                              void* d_out, int out_size, void* d_ws, size_t ws_size,
                              hipStream_t stream) {
    const float* x    = (const float*)d_in[0];
    const float* w_ih = (const float*)d_in[1];
    const float* w_hh = (const float*)d_in[2];
    const float* b_ih = (const float*)d_in[3];
    const float* b_hh = (const float*)d_in[4];
    float* out = (float*)d_out;

    // ws layout (~225 MB):
    //   xbf    : T*B*H bf16 = 64 MB
    //   h0seq  : T*B*H bf16 = 64 MB (write-once-read-once)
    //   h1seq  : T*B*H bf16 = 64 MB
    //   wi0b/wh0b/wi1b/wh1b : bf16 weights
    //   hf0,hf1,cb0,cb1 : B*H fp32 each
    //   flags  : 512 unsigned
    const size_t seqE = (size_t)T_LEN * BATCH * HID;
    const size_t BHs  = (size_t)BATCH * HID;

    bf16* xbf   = (bf16*)d_ws;
    bf16* h0seq = xbf + seqE;
    bf16* h1seq = h0seq + seqE;
    bf16* wi0b  = h1seq + seqE;
    bf16* wh0b  = wi0b + (size_t)GATES * IN_DIM;
    bf16* wi1b  = wh0b + (size_t)GATES * HID;
    bf16* wh1b  = wi1b + (size_t)GATES * HID;
    float* hf0  = (float*)(wh1b + (size_t)GATES * HID);
    float* hf1  = hf0 + BHs;
    float* cb0  = hf1 + BHs;
    float* cb1  = cb0 + BHs;
    unsigned* flags = (unsigned*)(cb1 + BHs);

    // conversions (parallel, off the critical chain)
    cvt_bf16<<<(int)(seqE / 4 + 255) / 256, 256, 0, stream>>>(x, xbf, (int)(seqE / 4));
    cvt_bf16<<<(GATES * IN_DIM / 4 + 255) / 256, 256, 0, stream>>>(
        w_ih, wi0b, GATES * IN_DIM / 4);
    cvt_bf16<<<(GATES * HID / 4 + 255) / 256, 256, 0, stream>>>(
        w_hh, wh0b, GATES * HID / 4);
    cvt_bf16<<<(GATES * HID / 4 + 255) / 256, 256, 0, stream>>>(
        w_ih + (size_t)GATES * IN_DIM, wi1b, GATES * HID / 4);
    cvt_bf16<<<(GATES * HID / 4 + 255) / 256, 256, 0, stream>>>(
        w_hh + (size_t)GATES * HID, wh1b, GATES * HID / 4);

    hipMemsetAsync(flags, 0, 512 * sizeof(unsigned), stream);

    void* args[15] = { (void*)&wi0b, (void*)&wh0b, (void*)&wi1b, (void*)&wh1b,
                       (void*)&b_ih, (void*)&b_hh, (void*)&xbf,
                       (void*)&h0seq, (void*)&h1seq, (void*)&out,
                       (void*)&hf0, (void*)&hf1, (void*)&cb0, (void*)&cb1,
                       (void*)&flags };
    hipLaunchCooperativeKernel((void*)lstm_fused, dim3(RBLK), dim3(256),
                               args, 0, stream);

    hipMemcpyAsync(out + seqE,           hf0, BHs * sizeof(float),
                   hipMemcpyDeviceToDevice, stream);
    hipMemcpyAsync(out + seqE + BHs,     hf1, BHs * sizeof(float),
                   hipMemcpyDeviceToDevice, stream);
    hipMemcpyAsync(out + seqE + 2 * BHs, cb0, BHs * sizeof(float),
                   hipMemcpyDeviceToDevice, stream);
    hipMemcpyAsync(out + seqE + 3 * BHs, cb1, BHs * sizeof(float),
                   hipMemcpyDeviceToDevice, stream);
}